// Round 7
// baseline (72313.629 us; speedup 1.0000x reference)
//
#include <hip/hip_runtime.h>
#include <stdint.h>
#include <math.h>

// Problem dims
#define Bn 256
#define Sn 512
#define En 256
#define Hn 256
#define Gn 1024            // 4*H
#define NSTEP 511          // S-1 decoder steps
#define MASK_VAL -100000.0

// Verified rounds 1-3: partitionable threefry + f64 compute path -> absmax=0.
#define PARTITIONABLE 1

// ---------------------------------------------------------------- threefry
__device__ __forceinline__ uint32_t rotl32(uint32_t v, int d) {
  return (v << d) | (v >> (32 - d));
}

__device__ __forceinline__ void threefry2x32(uint32_t k0, uint32_t k1,
                                             uint32_t x0, uint32_t x1,
                                             uint32_t& o0, uint32_t& o1) {
  const uint32_t ks2 = k0 ^ k1 ^ 0x1BD11BDAu;
  x0 += k0; x1 += k1;
  x0 += x1; x1 = rotl32(x1, 13); x1 ^= x0;
  x0 += x1; x1 = rotl32(x1, 15); x1 ^= x0;
  x0 += x1; x1 = rotl32(x1, 26); x1 ^= x0;
  x0 += x1; x1 = rotl32(x1,  6); x1 ^= x0;
  x0 += k1; x1 += ks2 + 1u;
  x0 += x1; x1 = rotl32(x1, 17); x1 ^= x0;
  x0 += x1; x1 = rotl32(x1, 29); x1 ^= x0;
  x0 += x1; x1 = rotl32(x1, 16); x1 ^= x0;
  x0 += x1; x1 = rotl32(x1, 24); x1 ^= x0;
  x0 += ks2; x1 += k0 + 2u;
  x0 += x1; x1 = rotl32(x1, 13); x1 ^= x0;
  x0 += x1; x1 = rotl32(x1, 15); x1 ^= x0;
  x0 += x1; x1 = rotl32(x1, 26); x1 ^= x0;
  x0 += x1; x1 = rotl32(x1,  6); x1 ^= x0;
  x0 += k0; x1 += k1 + 3u;
  x0 += x1; x1 = rotl32(x1, 17); x1 ^= x0;
  x0 += x1; x1 = rotl32(x1, 29); x1 ^= x0;
  x0 += x1; x1 = rotl32(x1, 16); x1 ^= x0;
  x0 += x1; x1 = rotl32(x1, 24); x1 ^= x0;
  x0 += k1; x1 += ks2 + 4u;
  x0 += x1; x1 = rotl32(x1, 13); x1 ^= x0;
  x0 += x1; x1 = rotl32(x1, 15); x1 ^= x0;
  x0 += x1; x1 = rotl32(x1, 26); x1 ^= x0;
  x0 += x1; x1 = rotl32(x1,  6); x1 ^= x0;
  x0 += ks2; x1 += k0 + 5u;
  o0 = x0; o1 = x1;
}

__device__ __forceinline__ uint32_t random_word(uint32_t k0, uint32_t k1, uint32_t n) {
#if PARTITIONABLE
  uint32_t o0, o1;
  threefry2x32(k0, k1, 0u, n, o0, o1);
  return o0 ^ o1;
#else
  const uint32_t half = (Bn * Sn) / 2;
  uint32_t lane = (n < half) ? n : (n - half);
  uint32_t o0, o1;
  threefry2x32(k0, k1, lane, lane + half, o0, o1);
  return (n < half) ? o0 : o1;
#endif
}

__device__ __forceinline__ double sigmoid64(double x) {
  return 1.0 / (1.0 + exp(-x));
}

// Opaque zero in a VGPR: forces dependent loads to VMEM (never SMEM/sL1),
// so the barrier's vector-cache fences guarantee freshness of mutated data.
__device__ __forceinline__ int opaque_zero() {
  int z = 0;
  asm volatile("" : "+v"(z));
  return z;
}

// Monotonic-epoch grid barrier. Co-residency is forced structurally:
// grid 256 = CU count, each block (16 waves, VGPR<=128, ~60KB LDS) fills one
// CU, so every CU hosts exactly one block. Bounded spin (~0.9s) bails out
// cleanly instead of hanging if that assumption ever breaks.
__device__ __forceinline__ int gsync(int* arrive, int epoch, int* okp) {
  __syncthreads();
  if (threadIdx.x == 0) {
    __hip_atomic_fetch_add(arrive, 1, __ATOMIC_RELEASE, __HIP_MEMORY_SCOPE_AGENT);
    int good = 1;
    long spins = 0;
    while (__hip_atomic_load(arrive, __ATOMIC_ACQUIRE, __HIP_MEMORY_SCOPE_AGENT) <
           256 * epoch) {
      __builtin_amdgcn_s_sleep(8);
      if (++spins > (1L << 22)) { good = 0; break; }
    }
    *okp = good;
  }
  __syncthreads();
  return *okp;
}

// ---------------------------------------------------------------- prep
__global__ __launch_bounds__(256) void k_wihe(const float* __restrict__ wemb,
                                              const float* __restrict__ wih,
                                              const float* __restrict__ bih,
                                              const float* __restrict__ bhh,
                                              double* __restrict__ wihe,
                                              double* __restrict__ bias) {
  int j = blockIdx.x * blockDim.x + threadIdx.x;
  if (j >= Gn) return;
  double a0 = 0.0, a1 = 0.0;
  for (int e = 0; e < En; ++e) {
    double w = (double)wih[j * En + e];
    a0 += (double)wemb[e] * w;
    a1 += (double)wemb[En + e] * w;
  }
  wihe[j] = a0;
  wihe[Gn + j] = a1;
  bias[j] = (double)bih[j] + (double)bhh[j];
}

__global__ __launch_bounds__(256) void k_keys(uint32_t* __restrict__ keys) {
  int j = blockIdx.x * blockDim.x + threadIdx.x;
  if (j >= NSTEP) return;
#if PARTITIONABLE
  uint32_t o0, o1;
  threefry2x32(0u, 1u, 0u, (uint32_t)j, o0, o1);
  keys[2 * j] = o0; keys[2 * j + 1] = o1;
#else
  uint32_t w[2];
  #pragma unroll
  for (int q = 0; q < 2; ++q) {
    uint32_t m = (uint32_t)(2 * j + q);
    uint32_t lane = (m < NSTEP) ? m : (m - NSTEP);
    uint32_t o0, o1;
    threefry2x32(0u, 1u, lane, lane + NSTEP, o0, o1);
    w[q] = (m < NSTEP) ? o0 : o1;
  }
  keys[2 * j] = w[0]; keys[2 * j + 1] = w[1];
#endif
}

// dst[k][j] = src[j][k]  (256x256 f32 transpose)
__global__ __launch_bounds__(256) void k_t32(const float* __restrict__ src,
                                             float* __restrict__ dst) {
  int idx = blockIdx.x * blockDim.x + threadIdx.x;
  int k = idx >> 8, j = idx & 255;
  dst[idx] = src[j * Hn + k];
}

__global__ __launch_bounds__(256) void k_init(double* __restrict__ hA, double* __restrict__ hB,
                                              int* __restrict__ mask, int* __restrict__ chosen,
                                              float* __restrict__ out, int* __restrict__ arrive) {
  int idx = blockIdx.x * blockDim.x + threadIdx.x;   // Bn*Sn threads
  if (idx < Bn * Hn) { hA[idx] = 0.0; hB[idx] = 0.0; }
  if (idx < Bn * Sn) mask[idx] = ((idx & (Sn - 1)) == 0) ? 1 : 0;
  if (idx < Bn) {
    chosen[idx] = 0;
    out[Bn * NSTEP + idx * Sn] = 0.0f;   // indices[:,0] = START
  }
  if (idx == 0) arrive[0] = 0;
}

// ---------------------------------------------------------------- persistent
// 256 blocks x 1024 threads (16 waves), 1 block/CU (structural).
// Cell tiling: bt = blk>>5 (8 b-tiles x 32 rows), ut = blk&31 (32 u-tiles x 8 units).
// Thread: wave w, lane l; row = b0 + w*2 + (l>>5); gr = l&31 = g*8+u.
// Weights: 32 gate-rows x 256 k f32 in LDS, pitch 258 (2-way = free).
// ref_proj is folded into the encoder: after each step's barrier, block b
// computes refT[b][t][s] = sum_k h[b][k]*Wref[t][k] from the f64 h (4-way
// split-k via wrefT, fixed (p0+p1)+(p2+p3) combine — q-proj's proven pattern).
// No hist buffer -> ws stays under the r3-proven ~145 MB (r4/r6's 268 MB
// double-buffer is the prime suspect for the memory-fault aborts).
struct AttnS {
  double qpart[4][256];
  double p2[2][512];
  double sl[512];
  double zz[512];
  float  qf[256];
  float  vbuf[256];
  int    sch;
  double slse;
};

__global__ __launch_bounds__(1024, 4) void k_persist(
    const float* __restrict__ inp,
    const double* __restrict__ wihe_e, const double* __restrict__ bias_e,
    const float* __restrict__ eWhh,
    const double* __restrict__ wihe_d, const double* __restrict__ bias_d,
    const float* __restrict__ dWhh,
    const float* __restrict__ wrefT, const float* __restrict__ wqT,
    const float* __restrict__ v,
    double* hA, double* hB, float* refT,
    int* maskp, int* chosen, const uint32_t* __restrict__ keys,
    float* out, int* arrive) {
  __shared__ float w32[32 * 258];
  __shared__ AttnS at;
  __shared__ int okf;

  const int tid = threadIdx.x;
  const int blk = blockIdx.x;
  const int w   = tid >> 6;
  const int l   = tid & 63;

  const int bt = blk >> 5, ut = blk & 31;
  const int b0 = bt * 32, u0 = ut * 8;
  const int row = b0 + w * 2 + (l >> 5);
  const int gr  = l & 31;
  const int g   = gr >> 3, u = gr & 7;
  const int jg  = g * 256 + u0 + u;

  const int zo = opaque_zero();
  int epoch = 0;
  double creg = 0.0;
  const double* hin = hA;
  double* hout = hB;
  const float* wrow = w32 + gr * 258;

  // ---- stage encoder weight tile (once)
  for (int idx = tid; idx < 32 * 256; idx += 1024) {
    int grs = idx >> 8, k = idx & 255;
    w32[grs * 258 + k] =
        eWhh[(size_t)((grs >> 3) * 256 + u0 + (grs & 7)) * 256 + k];
  }
  __syncthreads();

  // ================================================================ encoder
  {
    const double bj = bias_e[jg], w0j = wihe_e[jg], w1j = wihe_e[Gn + jg];
    for (int s = 0; s < Sn; ++s) {
      // ---- cell (r3 accumulation order: k ascending)
      {
        const double* hr = hin + (size_t)row * Hn + zo;
        double x0 = (double)inp[((size_t)row * Sn + s) * 2 + 0];
        double x1 = (double)inp[((size_t)row * Sn + s) * 2 + 1];
        double acc = bj + x0 * w0j + x1 * w1j;
        #pragma unroll 8
        for (int k = 0; k < Hn; ++k)
          acc += hr[k] * (double)wrow[k];
        const int base = l & 32, uu = l & 7;
        double gi = __shfl(acc, base + uu);
        double gf = __shfl(acc, base + 8 + uu);
        double gg = __shfl(acc, base + 16 + uu);
        double go = __shfl(acc, base + 24 + uu);
        if ((l & 31) < 8) {
          double cn = sigmoid64(gf) * creg + sigmoid64(gi) * tanh(gg);
          double hn = sigmoid64(go) * tanh(cn);
          creg = cn;
          hout[(size_t)row * Hn + u0 + uu] = hn;
        }
        const double* tp = hin; hin = hout; hout = (double*)tp;
      }
      if (!gsync(arrive, ++epoch, &okf)) return;

      // ---- ref_proj column s for b = blk (h now complete, f64)
      {
        const double* hb = hin + (size_t)blk * Hn + zo;
        const int part = tid >> 8, tcol = tid & 255;
        double acc = 0.0;
        #pragma unroll 8
        for (int i = 0; i < 64; ++i) {
          int k = part * 64 + i;
          acc += hb[k] * (double)wrefT[(size_t)k * Hn + tcol];
        }
        at.qpart[part][tcol] = acc;
        __syncthreads();
        if (tid < 256) {
          double r = (at.qpart[0][tid] + at.qpart[1][tid]) +
                     (at.qpart[2][tid] + at.qpart[3][tid]);
          refT[((size_t)blk * Hn + tid) * Sn + s] = (float)r;
        }
        // next write to qpart happens after the next gsync's __syncthreads
      }
    }
  }

  // ---- stage decoder weight tile
  __syncthreads();
  for (int idx = tid; idx < 32 * 256; idx += 1024) {
    int grs = idx >> 8, k = idx & 255;
    w32[grs * 258 + k] =
        dWhh[(size_t)((grs >> 3) * 256 + u0 + (grs & 7)) * 256 + k];
  }
  __syncthreads();

  // ================================================================ decoder
  {
    const double bj = bias_d[jg], w0j = wihe_d[jg], w1j = wihe_d[Gn + jg];
    const int b = blk;
    for (int t = 0; t < NSTEP; ++t) {
      // ---- cell (exact r3 accumulation order)
      {
        int col = chosen[row + zo];
        const double* hr = hin + (size_t)row * Hn + zo;
        double x0 = (double)inp[((size_t)row * Sn + col) * 2 + 0];
        double x1 = (double)inp[((size_t)row * Sn + col) * 2 + 1];
        double acc = bj + x0 * w0j + x1 * w1j;
        #pragma unroll 8
        for (int k = 0; k < Hn; ++k)
          acc += hr[k] * (double)wrow[k];
        const int base = l & 32, uu = l & 7;
        double gi = __shfl(acc, base + uu);
        double gf = __shfl(acc, base + 8 + uu);
        double gg = __shfl(acc, base + 16 + uu);
        double go = __shfl(acc, base + 24 + uu);
        if ((l & 31) < 8) {
          double cn = sigmoid64(gf) * creg + sigmoid64(gi) * tanh(gg);
          double hn = sigmoid64(go) * tanh(cn);
          creg = cn;
          hout[(size_t)row * Hn + u0 + uu] = hn;
        }
        const double* tp2 = hin; hin = hout; hout = (double*)tp2;
      }
      if (!gsync(arrive, ++epoch, &okf)) return;

      // ---- attention + sample (block b)
      {
        // q-projection: r3 order (64-k parts, (p0+p1)+(p2+p3))
        const double* hb = hin + (size_t)b * Hn + zo;
        const int part = tid >> 8, jq = tid & 255;
        double qa = 0.0;
        #pragma unroll 8
        for (int i = 0; i < 64; ++i) {
          int k = part * 64 + i;
          qa += hb[k] * (double)wqT[(size_t)k * Hn + jq];
        }
        at.qpart[part][jq] = qa;
        if (tid < 256) at.vbuf[tid] = v[tid];
        __syncthreads();
        if (tid < 256) {
          double q = (at.qpart[0][tid] + at.qpart[1][tid]) +
                     (at.qpart[2][tid] + at.qpart[3][tid]);
          at.qf[tid] = (float)q;
        }
        __syncthreads();
        // logits via refT: thread = (s, t-half); coalesced, no cross-lane reduce.
        // refT[b] was written by this very block -> no cross-CU coherence issue.
        {
          const int sE = tid & 511, ph = tid >> 9;
          const float* rT = refT + ((size_t)b * Hn + ph * 128) * Sn + sE;
          double la = 0.0;
          #pragma unroll 4
          for (int tt2 = 0; tt2 < 128; ++tt2) {
            float rr = rT[(size_t)tt2 * Sn];
            int tc2 = ph * 128 + tt2;
            float qv = at.qf[tc2];
            double vv = (double)at.vbuf[tc2];
            la += vv * (double)tanhf(qv + rr);
          }
          at.p2[ph][sE] = la;
        }
        __syncthreads();
        // mask + gumbel
        const uint32_t k0 = keys[2 * t], k1 = keys[2 * t + 1];
        if (tid < Sn) {
          double lg = maskp[(size_t)b * Sn + tid + zo]
                          ? (double)MASK_VAL
                          : (at.p2[0][tid] + at.p2[1][tid]);
          uint32_t n = (uint32_t)(b * Sn + tid);
          uint32_t wrd = random_word(k0, k1, n);
          float uf = __uint_as_float((wrd >> 9) | 0x3f800000u) - 1.0f;
          uf = fmaxf(uf, 1.17549435e-38f);
          double gn2 = -log(-log((double)uf));
          at.sl[tid] = lg;
          at.zz[tid] = lg + gn2;
        }
        __syncthreads();
        // argmax (wave 0, first-index tie-break) | logsumexp (wave 1)
        if (w == 0) {
          double bz = at.zz[l]; int bi = l;
          #pragma unroll
          for (int k = 1; k < 8; ++k) {
            int s2 = l + k * 64;
            double z2 = at.zz[s2];
            if (z2 > bz || (z2 == bz && s2 < bi)) { bz = z2; bi = s2; }
          }
          #pragma unroll
          for (int m = 32; m >= 1; m >>= 1) {
            double oz = __shfl_xor(bz, m);
            int    oi = __shfl_xor(bi, m);
            if (oz > bz || (oz == bz && oi < bi)) { bz = oz; bi = oi; }
          }
          if (l == 0) at.sch = bi;
        }
        if (w == 1) {
          double bm = at.sl[l];
          #pragma unroll
          for (int k = 1; k < 8; ++k) bm = fmax(bm, at.sl[l + k * 64]);
          #pragma unroll
          for (int m = 32; m >= 1; m >>= 1) bm = fmax(bm, __shfl_xor(bm, m));
          double ps = 0.0;
          #pragma unroll
          for (int k = 0; k < 8; ++k) ps += exp(at.sl[l + k * 64] - bm);
          #pragma unroll
          for (int m = 32; m >= 1; m >>= 1) ps += __shfl_xor(ps, m);
          if (l == 0) at.slse = bm + log(ps);
        }
        __syncthreads();
        if (tid == 0) {
          int ch = at.sch;
          double lp = at.sl[ch] - at.slse;
          out[(size_t)b * NSTEP + t] = (float)lp;
          out[(size_t)Bn * NSTEP + (size_t)b * Sn + (t + 1)] = (float)ch;
          maskp[(size_t)b * Sn + ch] = 1;
          chosen[b] = ch;
        }
      }
      if (!gsync(arrive, ++epoch, &okf)) return;
    }
  }
}

// ---------------------------------------------------------------- launch
extern "C" void kernel_launch(void* const* d_in, const int* in_sizes, int n_in,
                              void* d_out, int out_size, void* d_ws, size_t ws_size,
                              hipStream_t stream) {
  const float* inp  = (const float*)d_in[0];
  const float* wemb = (const float*)d_in[1];
  const float* eWih = (const float*)d_in[2];
  const float* eWhh = (const float*)d_in[3];
  const float* ebih = (const float*)d_in[4];
  const float* ebhh = (const float*)d_in[5];
  const float* dWih = (const float*)d_in[6];
  const float* dWhh = (const float*)d_in[7];
  const float* dbih = (const float*)d_in[8];
  const float* dbhh = (const float*)d_in[9];
  const float* Wq   = (const float*)d_in[10];
  const float* Wref = (const float*)d_in[11];
  const float* v    = (const float*)d_in[12];
  float* out = (float*)d_out;

  char* ws = (char*)d_ws;
  size_t off = 0;
  auto alloc = [&](size_t bytes) -> void* {
    void* p = (void*)(ws + off);
    off += (bytes + 255) & ~(size_t)255;
    return p;
  };
  // total ~136 MB — below the r3-proven ~145 MB workspace level
  float*    refT   = (float*)   alloc((size_t)Bn * Sn * Hn * sizeof(float));   // 134 MB
  double*   hA     = (double*)  alloc((size_t)Bn * Hn * sizeof(double));
  double*   hB     = (double*)  alloc((size_t)Bn * Hn * sizeof(double));
  float*    wqT    = (float*)   alloc((size_t)Hn * Hn * sizeof(float));
  float*    wrefT  = (float*)   alloc((size_t)Hn * Hn * sizeof(float));
  double*   wihe_e = (double*)  alloc(2 * Gn * sizeof(double));
  double*   wihe_d = (double*)  alloc(2 * Gn * sizeof(double));
  double*   bias_e = (double*)  alloc(Gn * sizeof(double));
  double*   bias_d = (double*)  alloc(Gn * sizeof(double));
  int*      maskp  = (int*)     alloc((size_t)Bn * Sn * sizeof(int));
  int*      chosen = (int*)     alloc(Bn * sizeof(int));
  uint32_t* keys   = (uint32_t*)alloc(2 * NSTEP * sizeof(uint32_t));
  int*      arrive = (int*)     alloc(256 * sizeof(int));
  (void)ws_size; (void)in_sizes; (void)n_in; (void)out_size;

  k_wihe<<<Gn / 256, 256, 0, stream>>>(wemb, eWih, ebih, ebhh, wihe_e, bias_e);
  k_wihe<<<Gn / 256, 256, 0, stream>>>(wemb, dWih, dbih, dbhh, wihe_d, bias_d);
  k_keys<<<2, 256, 0, stream>>>(keys);
  k_t32<<<(Hn * Hn) / 256, 256, 0, stream>>>(Wq, wqT);
  k_t32<<<(Hn * Hn) / 256, 256, 0, stream>>>(Wref, wrefT);
  k_init<<<(Bn * Sn) / 256, 256, 0, stream>>>(hA, hB, maskp, chosen, out, arrive);

  k_persist<<<256, 1024, 0, stream>>>(
      inp, wihe_e, bias_e, eWhh, wihe_d, bias_d, dWhh,
      wrefT, wqT, v, hA, hB, refT,
      maskp, chosen, keys, out, arrive);
}

// Round 8
// 40869.824 us; speedup vs baseline: 1.7694x; 1.7694x over previous
//
#include <hip/hip_runtime.h>
#include <stdint.h>
#include <math.h>

// Problem dims
#define Bn 256
#define Sn 512
#define En 256
#define Hn 256
#define Gn 1024            // 4*H
#define NSTEP 511          // S-1 decoder steps
#define MASK_VAL -100000.0

// Verified rounds 1-3,7: partitionable threefry + f64 compute path -> absmax=0.
#define PARTITIONABLE 1

// ---------------------------------------------------------------- threefry
__device__ __forceinline__ uint32_t rotl32(uint32_t v, int d) {
  return (v << d) | (v >> (32 - d));
}

__device__ __forceinline__ void threefry2x32(uint32_t k0, uint32_t k1,
                                             uint32_t x0, uint32_t x1,
                                             uint32_t& o0, uint32_t& o1) {
  const uint32_t ks2 = k0 ^ k1 ^ 0x1BD11BDAu;
  x0 += k0; x1 += k1;
  x0 += x1; x1 = rotl32(x1, 13); x1 ^= x0;
  x0 += x1; x1 = rotl32(x1, 15); x1 ^= x0;
  x0 += x1; x1 = rotl32(x1, 26); x1 ^= x0;
  x0 += x1; x1 = rotl32(x1,  6); x1 ^= x0;
  x0 += k1; x1 += ks2 + 1u;
  x0 += x1; x1 = rotl32(x1, 17); x1 ^= x0;
  x0 += x1; x1 = rotl32(x1, 29); x1 ^= x0;
  x0 += x1; x1 = rotl32(x1, 16); x1 ^= x0;
  x0 += x1; x1 = rotl32(x1, 24); x1 ^= x0;
  x0 += ks2; x1 += k0 + 2u;
  x0 += x1; x1 = rotl32(x1, 13); x1 ^= x0;
  x0 += x1; x1 = rotl32(x1, 15); x1 ^= x0;
  x0 += x1; x1 = rotl32(x1, 26); x1 ^= x0;
  x0 += x1; x1 = rotl32(x1,  6); x1 ^= x0;
  x0 += k0; x1 += k1 + 3u;
  x0 += x1; x1 = rotl32(x1, 17); x1 ^= x0;
  x0 += x1; x1 = rotl32(x1, 29); x1 ^= x0;
  x0 += x1; x1 = rotl32(x1, 16); x1 ^= x0;
  x0 += x1; x1 = rotl32(x1, 24); x1 ^= x0;
  x0 += k1; x1 += ks2 + 4u;
  x0 += x1; x1 = rotl32(x1, 13); x1 ^= x0;
  x0 += x1; x1 = rotl32(x1, 15); x1 ^= x0;
  x0 += x1; x1 = rotl32(x1, 26); x1 ^= x0;
  x0 += x1; x1 = rotl32(x1,  6); x1 ^= x0;
  x0 += ks2; x1 += k0 + 5u;
  o0 = x0; o1 = x1;
}

__device__ __forceinline__ uint32_t random_word(uint32_t k0, uint32_t k1, uint32_t n) {
#if PARTITIONABLE
  uint32_t o0, o1;
  threefry2x32(k0, k1, 0u, n, o0, o1);
  return o0 ^ o1;
#else
  const uint32_t half = (Bn * Sn) / 2;
  uint32_t lane = (n < half) ? n : (n - half);
  uint32_t o0, o1;
  threefry2x32(k0, k1, lane, lane + half, o0, o1);
  return (n < half) ? o0 : o1;
#endif
}

__device__ __forceinline__ double sigmoid64(double x) {
  return 1.0 / (1.0 + exp(-x));
}

// ---------------------------------------------------------------- prep
__global__ __launch_bounds__(256) void k_wihe(const float* __restrict__ wemb,
                                              const float* __restrict__ wih,
                                              const float* __restrict__ bih,
                                              const float* __restrict__ bhh,
                                              double* __restrict__ wihe,
                                              double* __restrict__ bias) {
  int j = blockIdx.x * blockDim.x + threadIdx.x;
  if (j >= Gn) return;
  double a0 = 0.0, a1 = 0.0;
  for (int e = 0; e < En; ++e) {
    double w = (double)wih[j * En + e];
    a0 += (double)wemb[e] * w;
    a1 += (double)wemb[En + e] * w;
  }
  wihe[j] = a0;
  wihe[Gn + j] = a1;
  bias[j] = (double)bih[j] + (double)bhh[j];
}

__global__ __launch_bounds__(256) void k_keys(uint32_t* __restrict__ keys) {
  int j = blockIdx.x * blockDim.x + threadIdx.x;
  if (j >= NSTEP) return;
#if PARTITIONABLE
  uint32_t o0, o1;
  threefry2x32(0u, 1u, 0u, (uint32_t)j, o0, o1);
  keys[2 * j] = o0; keys[2 * j + 1] = o1;
#else
  uint32_t w[2];
  #pragma unroll
  for (int q = 0; q < 2; ++q) {
    uint32_t m = (uint32_t)(2 * j + q);
    uint32_t lane = (m < NSTEP) ? m : (m - NSTEP);
    uint32_t o0, o1;
    threefry2x32(0u, 1u, lane, lane + NSTEP, o0, o1);
    w[q] = (m < NSTEP) ? o0 : o1;
  }
  keys[2 * j] = w[0]; keys[2 * j + 1] = w[1];
#endif
}

// dst[k][j] = src[j][k]  (256x256 f32 transpose: Wq, Wref)
__global__ __launch_bounds__(256) void k_t32(const float* __restrict__ src,
                                             float* __restrict__ dst) {
  int idx = blockIdx.x * blockDim.x + threadIdx.x;
  int k = idx >> 8, j = idx & 255;
  dst[idx] = src[j * Hn + k];
}

// dst[k][j] = src[j][k]  (Whh: 1024 rows j, 256 cols k -> 256 x 1024)
__global__ __launch_bounds__(256) void k_t32w(const float* __restrict__ src,
                                              float* __restrict__ dst) {
  int idx = blockIdx.x * blockDim.x + threadIdx.x;   // 256*1024 elems
  int k = idx >> 10, j = idx & 1023;
  dst[idx] = src[j * Hn + k];
}

__global__ __launch_bounds__(256) void k_init(float* __restrict__ out) {
  int idx = blockIdx.x * blockDim.x + threadIdx.x;
  if (idx < Bn) out[Bn * NSTEP + idx * Sn] = 0.0f;   // indices[:,0] = START
}

// ---------------------------------------------------------------- main
// Block b owns batch row b end-to-end: encoder 512 steps + refproj column
// writes, then decoder 511 steps with attention+sampling. h/c/mask/chosen
// live in LDS/registers -> ZERO grid synchronization, zero cross-block
// communication (the model has no cross-batch coupling). Weights stream
// from L2 (1 MB Whh^T is shared by all 32 blocks of an XCD -> L2-resident).
// All accumulation orders are copied bit-for-bit from the r7 kernel
// (absmax 0): gate j: bias + x-terms then k-ascending; refproj/qproj:
// 4-way split-k, (p0+p1)+(p2+p3) combine.
struct AttnS {
  double qpart[4][256];
  double p2[2][512];
  double sl[512];
  double zz[512];
  float  qf[256];
  float  vbuf[256];
  int    sch;
  double slse;
};

__global__ __launch_bounds__(1024, 4) void k_main(
    const float* __restrict__ inp,
    const double* __restrict__ wihe_e, const double* __restrict__ bias_e,
    const float* __restrict__ whhT_e,
    const double* __restrict__ wihe_d, const double* __restrict__ bias_d,
    const float* __restrict__ whhT_d,
    const float* __restrict__ wrefT, const float* __restrict__ wqT,
    const float* __restrict__ v,
    float* __restrict__ refT,
    const uint32_t* __restrict__ keys,
    float* __restrict__ out) {
  __shared__ double sh_h[Hn];     // current h (f64)
  __shared__ double sh_g[Gn];     // gates
  __shared__ AttnS at;
  __shared__ int smask[Sn];
  __shared__ int schosen;

  const int b   = blockIdx.x;
  const int tid = threadIdx.x;
  const int w   = tid >> 6;
  const int l   = tid & 63;

  // per-thread gate-row constants (j = tid)
  const double bj_e = bias_e[tid], w0e = wihe_e[tid], w1e = wihe_e[Gn + tid];
  const double bj_d = bias_d[tid], w0d = wihe_d[tid], w1d = wihe_d[Gn + tid];

  double creg = 0.0;              // c for unit u = tid (threads 0..255)
  if (tid < Hn) sh_h[tid] = 0.0;
  if (tid < Sn) smask[tid] = (tid == 0) ? 1 : 0;
  if (tid < Hn) at.vbuf[tid] = v[tid];
  if (tid == 0) schosen = 0;
  __syncthreads();

  const float* wcol_e = whhT_e + tid;
  const float* wcol_d = whhT_d + tid;
  const int part = tid >> 8, tcol = tid & 255;

  // ================================================================ encoder
  for (int s = 0; s < Sn; ++s) {
    // cell: gate j = tid, exact r7 accumulation order
    {
      double x0 = (double)inp[((size_t)b * Sn + s) * 2 + 0];
      double x1 = (double)inp[((size_t)b * Sn + s) * 2 + 1];
      double acc = bj_e + x0 * w0e + x1 * w1e;
      #pragma unroll 8
      for (int k = 0; k < Hn; ++k)
        acc += sh_h[k] * (double)wcol_e[(size_t)k << 10];
      sh_g[tid] = acc;
    }
    __syncthreads();                       // S1: gates ready, h reads done
    if (tid < Hn) {
      double gi = sh_g[tid];
      double gf = sh_g[256 + tid];
      double gg = sh_g[512 + tid];
      double go = sh_g[768 + tid];
      double cn = sigmoid64(gf) * creg + sigmoid64(gi) * tanh(gg);
      double hn = sigmoid64(go) * tanh(cn);
      creg = cn;
      sh_h[tid] = hn;
    }
    __syncthreads();                       // S2: h ready
    // refproj column s: r7's verified split-k pattern, h in f64
    {
      double racc = 0.0;
      #pragma unroll 8
      for (int i = 0; i < 64; ++i) {
        int k = part * 64 + i;
        racc += sh_h[k] * (double)wrefT[(size_t)k * Hn + tcol];
      }
      at.qpart[part][tcol] = racc;
    }
    __syncthreads();                       // S3: qpart ready
    if (tid < Hn) {
      double r = (at.qpart[0][tid] + at.qpart[1][tid]) +
                 (at.qpart[2][tid] + at.qpart[3][tid]);
      refT[((size_t)b * Hn + tid) * Sn + s] = (float)r;
    }
    // no trailing sync needed: next qpart write is separated by S1/S2
  }

  // ================================================================ decoder
  for (int t = 0; t < NSTEP; ++t) {
    // cell (chosen/mask/h all block-local)
    {
      int col = schosen;
      double x0 = (double)inp[((size_t)b * Sn + col) * 2 + 0];
      double x1 = (double)inp[((size_t)b * Sn + col) * 2 + 1];
      double acc = bj_d + x0 * w0d + x1 * w1d;
      #pragma unroll 8
      for (int k = 0; k < Hn; ++k)
        acc += sh_h[k] * (double)wcol_d[(size_t)k << 10];
      sh_g[tid] = acc;
    }
    __syncthreads();                       // S1
    if (tid < Hn) {
      double gi = sh_g[tid];
      double gf = sh_g[256 + tid];
      double gg = sh_g[512 + tid];
      double go = sh_g[768 + tid];
      double cn = sigmoid64(gf) * creg + sigmoid64(gi) * tanh(gg);
      double hn = sigmoid64(go) * tanh(cn);
      creg = cn;
      sh_h[tid] = hn;
    }
    __syncthreads();                       // S2: h ready
    // q-projection (r7 pattern)
    {
      double qa = 0.0;
      #pragma unroll 8
      for (int i = 0; i < 64; ++i) {
        int k = part * 64 + i;
        qa += sh_h[k] * (double)wqT[(size_t)k * Hn + tcol];
      }
      at.qpart[part][tcol] = qa;
    }
    __syncthreads();                       // S3
    if (tid < Hn) {
      double q = (at.qpart[0][tid] + at.qpart[1][tid]) +
                 (at.qpart[2][tid] + at.qpart[3][tid]);
      at.qf[tid] = (float)q;
    }
    __syncthreads();                       // S4: qf ready
    // logits via refT (this block's own rows; coalesced, no cross-lane reduce)
    {
      const int sE = tid & 511, ph = tid >> 9;
      const float* rT = refT + ((size_t)b * Hn + ph * 128) * Sn + sE;
      double la = 0.0;
      #pragma unroll 4
      for (int tt2 = 0; tt2 < 128; ++tt2) {
        float rr = rT[(size_t)tt2 * Sn];
        int tc2 = ph * 128 + tt2;
        float qv = at.qf[tc2];
        double vv = (double)at.vbuf[tc2];
        la += vv * (double)tanhf(qv + rr);
      }
      at.p2[ph][sE] = la;
    }
    __syncthreads();                       // S5
    // mask + gumbel
    const uint32_t k0 = keys[2 * t], k1 = keys[2 * t + 1];
    if (tid < Sn) {
      double lg = smask[tid] ? (double)MASK_VAL
                             : (at.p2[0][tid] + at.p2[1][tid]);
      uint32_t n = (uint32_t)(b * Sn + tid);
      uint32_t wrd = random_word(k0, k1, n);
      float uf = __uint_as_float((wrd >> 9) | 0x3f800000u) - 1.0f;
      uf = fmaxf(uf, 1.17549435e-38f);
      double gn2 = -log(-log((double)uf));
      at.sl[tid] = lg;
      at.zz[tid] = lg + gn2;
    }
    __syncthreads();                       // S6
    // argmax (wave 0, first-index tie-break) | logsumexp (wave 1)
    if (w == 0) {
      double bz = at.zz[l]; int bi = l;
      #pragma unroll
      for (int k = 1; k < 8; ++k) {
        int s2 = l + k * 64;
        double z2 = at.zz[s2];
        if (z2 > bz || (z2 == bz && s2 < bi)) { bz = z2; bi = s2; }
      }
      #pragma unroll
      for (int m = 32; m >= 1; m >>= 1) {
        double oz = __shfl_xor(bz, m);
        int    oi = __shfl_xor(bi, m);
        if (oz > bz || (oz == bz && oi < bi)) { bz = oz; bi = oi; }
      }
      if (l == 0) at.sch = bi;
    }
    if (w == 1) {
      double bm = at.sl[l];
      #pragma unroll
      for (int k = 1; k < 8; ++k) bm = fmax(bm, at.sl[l + k * 64]);
      #pragma unroll
      for (int m = 32; m >= 1; m >>= 1) bm = fmax(bm, __shfl_xor(bm, m));
      double ps = 0.0;
      #pragma unroll
      for (int k = 0; k < 8; ++k) ps += exp(at.sl[l + k * 64] - bm);
      #pragma unroll
      for (int m = 32; m >= 1; m >>= 1) ps += __shfl_xor(ps, m);
      if (l == 0) at.slse = bm + log(ps);
    }
    __syncthreads();                       // S7
    if (tid == 0) {
      int ch = at.sch;
      double lp = at.sl[ch] - at.slse;
      out[(size_t)b * NSTEP + t] = (float)lp;
      out[(size_t)Bn * NSTEP + (size_t)b * Sn + (t + 1)] = (float)ch;
      smask[ch] = 1;
      schosen = ch;
    }
    __syncthreads();                       // S8: chosen/mask ready
  }
}

// ---------------------------------------------------------------- launch
extern "C" void kernel_launch(void* const* d_in, const int* in_sizes, int n_in,
                              void* d_out, int out_size, void* d_ws, size_t ws_size,
                              hipStream_t stream) {
  const float* inp  = (const float*)d_in[0];
  const float* wemb = (const float*)d_in[1];
  const float* eWih = (const float*)d_in[2];
  const float* eWhh = (const float*)d_in[3];
  const float* ebih = (const float*)d_in[4];
  const float* ebhh = (const float*)d_in[5];
  const float* dWih = (const float*)d_in[6];
  const float* dWhh = (const float*)d_in[7];
  const float* dbih = (const float*)d_in[8];
  const float* dbhh = (const float*)d_in[9];
  const float* Wq   = (const float*)d_in[10];
  const float* Wref = (const float*)d_in[11];
  const float* v    = (const float*)d_in[12];
  float* out = (float*)d_out;

  char* ws = (char*)d_ws;
  size_t off = 0;
  auto alloc = [&](size_t bytes) -> void* {
    void* p = (void*)(ws + off);
    off += (bytes + 255) & ~(size_t)255;
    return p;
  };
  // total ~137 MB (r3-proven workspace level)
  float*    refT   = (float*)   alloc((size_t)Bn * Sn * Hn * sizeof(float));   // 134 MB
  float*    whhT_e = (float*)   alloc((size_t)Hn * Gn * sizeof(float));        // 1 MB
  float*    whhT_d = (float*)   alloc((size_t)Hn * Gn * sizeof(float));        // 1 MB
  float*    wqT    = (float*)   alloc((size_t)Hn * Hn * sizeof(float));
  float*    wrefT  = (float*)   alloc((size_t)Hn * Hn * sizeof(float));
  double*   wihe_e = (double*)  alloc(2 * Gn * sizeof(double));
  double*   wihe_d = (double*)  alloc(2 * Gn * sizeof(double));
  double*   bias_e = (double*)  alloc(Gn * sizeof(double));
  double*   bias_d = (double*)  alloc(Gn * sizeof(double));
  uint32_t* keys   = (uint32_t*)alloc(2 * NSTEP * sizeof(uint32_t));
  (void)ws_size; (void)in_sizes; (void)n_in; (void)out_size;

  k_wihe<<<Gn / 256, 256, 0, stream>>>(wemb, eWih, ebih, ebhh, wihe_e, bias_e);
  k_wihe<<<Gn / 256, 256, 0, stream>>>(wemb, dWih, dbih, dbhh, wihe_d, bias_d);
  k_keys<<<2, 256, 0, stream>>>(keys);
  k_t32<<<(Hn * Hn) / 256, 256, 0, stream>>>(Wq, wqT);
  k_t32<<<(Hn * Hn) / 256, 256, 0, stream>>>(Wref, wrefT);
  k_t32w<<<(Hn * Gn) / 256, 256, 0, stream>>>(eWhh, whhT_e);
  k_t32w<<<(Hn * Gn) / 256, 256, 0, stream>>>(dWhh, whhT_d);
  k_init<<<1, 256, 0, stream>>>(out);

  k_main<<<Bn, 1024, 0, stream>>>(
      inp, wihe_e, bias_e, whhT_e, wihe_d, bias_d, whhT_d,
      wrefT, wqT, v, refT, keys, out);
}